// Round 6
// baseline (220.811 us; speedup 1.0000x reference)
//
#include <hip/hip_runtime.h>
#include <stdint.h>

typedef float f32x4 __attribute__((ext_vector_type(4)));
typedef float f32x16 __attribute__((ext_vector_type(16)));
typedef __bf16 bf16x8 __attribute__((ext_vector_type(8)));
typedef unsigned int u32x4 __attribute__((ext_vector_type(4)));
typedef unsigned short u16x4 __attribute__((ext_vector_type(4)));

#define DEV __device__ __forceinline__

// SCALE * log2(e): softmax computed base-2 (exact-equivalent)
#define QSCALE_LOG2E 0.18033688011112042f

// round-to-nearest-even f32 -> bf16 bits
DEV unsigned short f2bf(float f) {
    unsigned u = __builtin_bit_cast(unsigned, f);
    u += 0x7fffu + ((u >> 16) & 1u);
    return (unsigned short)(u >> 16);
}

// native cast path: compiler emits v_cvt_pk_bf16_f32 for pairs (RNE)
DEV unsigned pack2bf(float a, float b) {
    unsigned short ua = __builtin_bit_cast(unsigned short, (__bf16)a);
    unsigned short ub = __builtin_bit_cast(unsigned short, (__bf16)b);
    return (unsigned)ua | ((unsigned)ub << 16);
}

// lane i <-> lane i^32 pairwise exchange of two registers (gfx950)
DEV void pswap(unsigned& a, unsigned& b) {
    asm volatile("v_permlane32_swap_b32 %0, %1" : "+v"(a), "+v"(b));
}

// async global->LDS, 16B per lane. LDS dst must be wave-uniform-base + lane*16.
DEV void gload16(const void* g, void* l) {
    __builtin_amdgcn_global_load_lds(
        (const __attribute__((address_space(1))) unsigned int*)(uintptr_t)g,
        (__attribute__((address_space(3))) unsigned int*)(unsigned int)(uintptr_t)l,
        16, 0, 0);
}

// ---------------- fp32 -> bf16 elementwise ----------------
__global__ void k_cvt(const float* __restrict__ in, unsigned short* __restrict__ out, int n4) {
    int i = blockIdx.x * 256 + threadIdx.x;
    int st = gridDim.x * 256;
    for (; i < n4; i += st) {
        f32x4 v = *(const f32x4*)(in + (size_t)i * 4);
        u16x4 o;
        o[0] = f2bf(v[0]); o[1] = f2bf(v[1]); o[2] = f2bf(v[2]); o[3] = f2bf(v[3]);
        *(u16x4*)(out + (size_t)i * 4) = o;
    }
}

// ---------------- fp32 [1024][Nc] -> bf16 [Nc][1024] transpose ----------------
__global__ void k_transpose(const float* __restrict__ in, unsigned short* __restrict__ out, int Nc) {
    __shared__ unsigned short tl[64][68];
    int n0 = blockIdx.x * 64, k0 = blockIdx.y * 64;
#pragma unroll
    for (int i = 0; i < 16; i++) {
        int idx = i * 256 + threadIdx.x;
        int kr = idx >> 6, nc = idx & 63;
        tl[kr][nc] = f2bf(in[(size_t)(k0 + kr) * Nc + n0 + nc]);
    }
    __syncthreads();
#pragma unroll
    for (int i = 0; i < 8; i++) {
        int idx = i * 256 + threadIdx.x;
        int nr = idx >> 5, kp2 = idx & 31;
        unsigned vv = (unsigned)tl[kp2 * 2][nr] | ((unsigned)tl[kp2 * 2 + 1][nr] << 16);
        *(unsigned*)(out + (size_t)(n0 + nr) * 1024 + k0 + kp2 * 2) = vv;
    }
}

// ---------------- GEMM: C[M][N] = A[M][K] * Bt[N][K]^T  (bf16 in, fp32 acc) ----
// MODE 1: scatter q (scaled by SCALE*log2e) / k to [B][H][N][D]; V TRANSPOSED
//         to vT [B][H][D][N].  MODE 3: out fp32 = C + bias (N fixed 1024)
// XCD-aware bijective block swizzle (T1): nwg is 768 / 256, both %8 == 0.
template <int MODE>
__global__ __launch_bounds__(256) void k_gemm(
    const unsigned short* __restrict__ A, const unsigned short* __restrict__ Bt, int K,
    unsigned short* __restrict__ q, unsigned short* __restrict__ kk_,
    unsigned short* __restrict__ vT, const float* __restrict__ bias,
    float* __restrict__ outf) {
    __shared__ unsigned short As[128 * 64];
    __shared__ unsigned short Bs[128 * 64];
    const int tid = threadIdx.x;
    const int w = tid >> 6, l = tid & 63, g = l >> 4, lr = l & 15;
    const int wr = w >> 1, wc = w & 1;
    const int nwg = gridDim.x * gridDim.y, cpx = nwg >> 3;
    const int lin = blockIdx.y * gridDim.x + blockIdx.x;
    const int swz = (lin & 7) * cpx + (lin >> 3);
    const int m0 = (swz / gridDim.x) * 128, n0 = (swz % gridDim.x) * 128;
    f32x4 acc[4][4] = {};

    for (int k0 = 0; k0 < K; k0 += 64) {
        __syncthreads();
#pragma unroll
        for (int i = 0; i < 4; i++) {
            int c = i * 256 + tid;
            gload16(A + (size_t)(m0 + (c >> 3)) * K + k0 + (c & 7) * 8, (char*)As + c * 16);
            gload16(Bt + (size_t)(n0 + (c >> 3)) * K + k0 + (c & 7) * 8, (char*)Bs + c * 16);
        }
        __syncthreads();
#pragma unroll
        for (int kk = 0; kk < 2; kk++) {
            bf16x8 af[4], bfv[4];
#pragma unroll
            for (int mi = 0; mi < 4; mi++)
                af[mi] = *(const bf16x8*)(As + (wr * 64 + mi * 16 + lr) * 64 + kk * 32 + g * 8);
#pragma unroll
            for (int ni = 0; ni < 4; ni++)
                bfv[ni] = *(const bf16x8*)(Bs + (wc * 64 + ni * 16 + lr) * 64 + kk * 32 + g * 8);
#pragma unroll
            for (int mi = 0; mi < 4; mi++)
#pragma unroll
                for (int ni = 0; ni < 4; ni++)
                    acc[mi][ni] = __builtin_amdgcn_mfma_f32_16x16x32_bf16(af[mi], bfv[ni], acc[mi][ni], 0, 0, 0);
        }
    }

#pragma unroll
    for (int mi = 0; mi < 4; mi++) {
#pragma unroll
        for (int ni = 0; ni < 4; ni++) {
            if (MODE == 1) {
                int row0 = m0 + wr * 64 + mi * 16 + g * 4;   // 4-aligned, no b-crossing
                int col = n0 + wc * 64 + ni * 16 + lr;
                int b = row0 >> 11, nn = row0 & 2047;
                int which = col >> 10, cc = col & 1023;
                int h = cc >> 6, d = cc & 63;
                if (which == 2) {
                    u16x4 pv;
#pragma unroll
                    for (int r = 0; r < 4; r++) pv[r] = f2bf(acc[mi][ni][r]);
                    *(u16x4*)&vT[((size_t)(b * 16 + h) * 64 + d) * 2048 + nn] = pv;
                } else {
                    unsigned short* dst = (which == 0) ? q : kk_;
                    const float sc = (which == 0) ? QSCALE_LOG2E : 1.f;
#pragma unroll
                    for (int r = 0; r < 4; r++)
                        dst[((size_t)(b * 16 + h) * 2048 + nn + r) * 64 + d] = f2bf(acc[mi][ni][r] * sc);
                }
            } else {
#pragma unroll
                for (int r = 0; r < 4; r++) {
                    int row = m0 + wr * 64 + mi * 16 + g * 4 + r;
                    int col = n0 + wc * 64 + ni * 16 + lr;
                    outf[(size_t)row * 1024 + col] = acc[mi][ni][r] + bias[col];
                }
            }
        }
    }
}

// ---------------- flash attention: in-block KV split, barrier-free loop --------
// Block = 128 thr (2 waves), both waves own the SAME 32 q-rows; wave w covers
// KV half [w*1024, w*1024+1024) in tiles of 32. K/V wave-private single-buffer
// LDS (chunk-major -> contiguous-512B ds_read_b128, zero conflicts; linear
// global_load_lds dests). NO __syncthreads in the loop -- only wave-local
// vmcnt/lgkmcnt. XCD-grouped decode: one head's blocks share one XCD's L2.
// End: exact flash merge of the two halves via LDS (2 barriers total).
__global__ __launch_bounds__(128, 4) void k_attn(
    const unsigned short* __restrict__ qb, const unsigned short* __restrict__ kb,
    const unsigned short* __restrict__ vTb, unsigned short* __restrict__ ao) {
    __shared__ __align__(16) char smem[16384];   // per wave: K 4KB + V 4KB
    const int tid = threadIdx.x;
    const int w = tid >> 6, l = tid & 63, l31 = l & 31, hf = l >> 5;
    // XCD-grouped decode: 2048 blocks = 8 xcd x 4 bh x 64 qb
    const int bid = blockIdx.x;
    const int xcd = bid & 7, slot = bid >> 3;
    const int bh = xcd * 4 + (slot >> 6), qb_ = slot & 63;
    const int b = bh >> 4, h = bh & 15;
    const unsigned short* qp = qb + (size_t)bh * 131072;
    const unsigned short* kp = kb + (size_t)bh * 131072 + (size_t)w * 65536;   // + w*1024 rows
    const unsigned short* vTp = vTb + (size_t)bh * 131072 + w * 1024;          // [d][n], col +w*1024
    char* Kl = smem + w * 8192;
    char* Vl = smem + w * 8192 + 4096;

    // Q fragment (B-operand of swapped QK^T): Q[q0+l31][d = dc*16 + hf*8 + j]
    const int qrow = qb_ * 32 + l31;
    bf16x8 qf[4];
#pragma unroll
    for (int dc = 0; dc < 4; dc++)
        qf[dc] = *(const bf16x8*)(qp + (size_t)qrow * 64 + dc * 16 + hf * 8);

    f32x16 o_acc[2] = {};   // O^T[d = (r&3)+8(r>>2)+4hf+32dt][q=l31]
    float m_r = -1e30f, l_r = 0.f;

    // ---- prologue: stage tile 0 (wave-private) ----
#pragma unroll
    for (int i = 0; i < 4; i++)
        gload16(kp + (size_t)l31 * 64 + (2 * i + hf) * 8, Kl + (i * 64 + l) * 16);
#pragma unroll
    for (int i = 0; i < 4; i++)
        gload16(vTp + (size_t)l * 2048 + i * 8, Vl + (i * 64 + l) * 16);

    for (int t = 0; t < 32; ++t) {
        asm volatile("s_waitcnt vmcnt(0)" ::: "memory");   // K(t),V(t) landed (wave-local)
        __builtin_amdgcn_sched_barrier(0);

        // ---- S^T = K x Q (one 32x32 tile, k=64 over 4 chunks) ----
        f32x16 s = {};
        __builtin_amdgcn_s_setprio(1);
#pragma unroll
        for (int dc = 0; dc < 4; dc++) {
            bf16x8 kf = *(const bf16x8*)(Kl + (((2 * dc + hf) * 32 + l31) * 16));
            s = __builtin_amdgcn_mfma_f32_32x32x16_bf16(kf, qf[dc], s, 0, 0, 0);
        }
        __builtin_amdgcn_s_setprio(0);
        // K LDS reads drained -> safe to overwrite buffer with next tile's DMA
        asm volatile("s_waitcnt lgkmcnt(0)" ::: "memory");
        __builtin_amdgcn_sched_barrier(0);
        if (t < 31) {
            const int kv0n = (t + 1) * 32;
#pragma unroll
            for (int i = 0; i < 4; i++)
                gload16(kp + (size_t)(kv0n + l31) * 64 + (2 * i + hf) * 8, Kl + (i * 64 + l) * 16);
        }

        // ---- lane-local online softmax (base 2), q-row l31 (split by hf) ----
        float ma = fmaxf(fmaxf(s[0], s[1]), fmaxf(s[2], s[3]));
        float mb = fmaxf(fmaxf(s[4], s[5]), fmaxf(s[6], s[7]));
        float mc = fmaxf(fmaxf(s[8], s[9]), fmaxf(s[10], s[11]));
        float md = fmaxf(fmaxf(s[12], s[13]), fmaxf(s[14], s[15]));
        float mx = fmaxf(fmaxf(ma, mb), fmaxf(mc, md));
        mx = fmaxf(mx, __shfl_xor(mx, 32));
        if (!__all(mx <= m_r + 8.f)) {   // defer-max (T13)
            float mn = fmaxf(m_r, mx);
            float fac = __builtin_amdgcn_exp2f(m_r - mn);
            m_r = mn;
            l_r *= fac;
#pragma unroll
            for (int r = 0; r < 16; r++) { o_acc[0][r] *= fac; o_acc[1][r] *= fac; }
        }
        float s0 = 0.f, s1 = 0.f, s2 = 0.f, s3 = 0.f;
#pragma unroll
        for (int r = 0; r < 16; r += 4) {
            float p0 = __builtin_amdgcn_exp2f(s[r] - m_r);
            float p1 = __builtin_amdgcn_exp2f(s[r + 1] - m_r);
            float p2 = __builtin_amdgcn_exp2f(s[r + 2] - m_r);
            float p3 = __builtin_amdgcn_exp2f(s[r + 3] - m_r);
            s[r] = p0; s[r + 1] = p1; s[r + 2] = p2; s[r + 3] = p3;
            s0 += p0; s1 += p1; s2 += p2; s3 += p3;
        }
        float ssum = (s0 + s1) + (s2 + s3);
        ssum += __shfl_xor(ssum, 32);
        l_r += ssum;

        // ---- pack P -> bf16, permlane32_swap -> PV B-frags ----
        unsigned wd[8];
#pragma unroll
        for (int i = 0; i < 8; i++) wd[i] = pack2bf(s[2 * i], s[2 * i + 1]);
        bf16x8 pf[2];
#pragma unroll
        for (int cl = 0; cl < 2; cl++) {
            unsigned b0 = wd[4 * cl + 0], b2 = wd[4 * cl + 2];
            unsigned b1 = wd[4 * cl + 1], b3 = wd[4 * cl + 3];
            pswap(b0, b2);
            pswap(b1, b3);
            u32x4 bw; bw[0] = b0; bw[1] = b1; bw[2] = b2; bw[3] = b3;
            pf[cl] = __builtin_bit_cast(bf16x8, bw);
        }

        // ---- O^T += V^T x P ----
        __builtin_amdgcn_s_setprio(1);
#pragma unroll
        for (int c = 0; c < 2; c++)
#pragma unroll
            for (int dt = 0; dt < 2; dt++) {
                bf16x8 vf = *(const bf16x8*)(Vl + (((2 * c + hf) * 64 + dt * 32 + l31) * 16));
                o_acc[dt] = __builtin_amdgcn_mfma_f32_32x32x16_bf16(vf, pf[c], o_acc[dt], 0, 0, 0);
            }
        __builtin_amdgcn_s_setprio(0);
        asm volatile("s_waitcnt lgkmcnt(0)" ::: "memory");
        __builtin_amdgcn_sched_barrier(0);
        if (t < 31) {
            const int kv0n = (t + 1) * 32;
#pragma unroll
            for (int i = 0; i < 4; i++)
                gload16(vTp + (size_t)l * 2048 + kv0n + i * 8, Vl + (i * 64 + l) * 16);
        }
    }

    // ---- merge the two KV halves (exact flash merge) ----
    __syncthreads();
    float* dumpO = (float*)smem;            // [64][34] padded (2-way max conflicts)
    float* dumpM = (float*)(smem + 8704);   // [64]
    float* dumpL = (float*)(smem + 8960);   // [64]
    if (w == 1) {
#pragma unroll
        for (int i = 0; i < 16; i++) dumpO[l * 34 + i] = o_acc[0][i];
#pragma unroll
        for (int i = 0; i < 16; i++) dumpO[l * 34 + 16 + i] = o_acc[1][i];
        dumpM[l] = m_r;
        dumpL[l] = l_r;
    }
    __syncthreads();
    if (w == 0) {
        float m1 = dumpM[l], l1 = dumpL[l];
        float m = fmaxf(m_r, m1);
        float a0 = __builtin_amdgcn_exp2f(m_r - m);
        float a1 = __builtin_amdgcn_exp2f(m1 - m);
        float linv = 1.f / (l_r * a0 + l1 * a1);
        float c0 = a0 * linv, c1 = a1 * linv;
        unsigned short* aop = ao + ((size_t)b * 2048 + qrow) * 1024 + h * 64;
#pragma unroll
        for (int dt = 0; dt < 2; dt++)
#pragma unroll
            for (int rg = 0; rg < 4; rg++) {
                u16x4 pv;
#pragma unroll
                for (int k = 0; k < 4; k++) {
                    int r = rg * 4 + k;
                    pv[k] = f2bf(o_acc[dt][r] * c0 + dumpO[l * 34 + dt * 16 + r] * c1);
                }
                *(u16x4*)(aop + 8 * rg + 4 * hf + 32 * dt) = pv;
            }
    }
}

extern "C" void kernel_launch(void* const* d_in, const int* in_sizes, int n_in,
                              void* d_out, int out_size, void* d_ws, size_t ws_size,
                              hipStream_t stream) {
    (void)in_sizes; (void)n_in; (void)out_size; (void)ws_size;
    const float* x      = (const float*)d_in[0];
    const float* w_qkv  = (const float*)d_in[1];
    const float* w_proj = (const float*)d_in[2];
    const float* b_proj = (const float*)d_in[3];
    float* out = (float*)d_out;
    char* ws = (char*)d_ws;

    // workspace layout (bytes); ao aliases xb (xb dead after GEMM1)
    unsigned short* xb     = (unsigned short*)(ws);             // [4096][1024] bf16
    unsigned short* ao     = (unsigned short*)(ws);             // [4096][1024] bf16 (alias)
    unsigned short* wqkvT  = (unsigned short*)(ws + 8388608);   // [3072][1024] bf16
    unsigned short* wprojT = (unsigned short*)(ws + 14680064);  // [1024][1024] bf16
    unsigned short* qb     = (unsigned short*)(ws + 16777216);  // [2][16][2048][64] bf16
    unsigned short* kb     = (unsigned short*)(ws + 25165824);  // [2][16][2048][64] bf16
    unsigned short* vTb    = (unsigned short*)(ws + 33554432);  // [2][16][64][2048] bf16

    k_cvt<<<2048, 256, 0, stream>>>(x, xb, 1048576);
    k_transpose<<<dim3(48, 16), 256, 0, stream>>>(w_qkv, wqkvT, 3072);
    k_transpose<<<dim3(16, 16), 256, 0, stream>>>(w_proj, wprojT, 1024);
    k_gemm<1><<<dim3(24, 32), 256, 0, stream>>>(xb, wqkvT, 1024, qb, kb, vTb, nullptr, nullptr);
    k_attn<<<2048, 128, 0, stream>>>(qb, kb, vTb, ao);
    k_gemm<3><<<dim3(8, 32), 256, 0, stream>>>(ao, wprojT, 1024, nullptr, nullptr, nullptr, b_proj, out);
}

// Round 7
// 163.980 us; speedup vs baseline: 1.3466x; 1.3466x over previous
//
#include <hip/hip_runtime.h>
#include <stdint.h>

typedef float f32x4 __attribute__((ext_vector_type(4)));
typedef float f32x16 __attribute__((ext_vector_type(16)));
typedef __bf16 bf16x8 __attribute__((ext_vector_type(8)));
typedef unsigned int u32x4 __attribute__((ext_vector_type(4)));
typedef unsigned short u16x4 __attribute__((ext_vector_type(4)));

#define DEV __device__ __forceinline__

// SCALE * log2(e): softmax computed base-2 (exact-equivalent)
#define QSCALE_LOG2E 0.18033688011112042f

// round-to-nearest-even f32 -> bf16 bits
DEV unsigned short f2bf(float f) {
    unsigned u = __builtin_bit_cast(unsigned, f);
    u += 0x7fffu + ((u >> 16) & 1u);
    return (unsigned short)(u >> 16);
}

// native cast path: compiler emits v_cvt_pk_bf16_f32 for pairs (RNE)
DEV unsigned pack2bf(float a, float b) {
    unsigned short ua = __builtin_bit_cast(unsigned short, (__bf16)a);
    unsigned short ub = __builtin_bit_cast(unsigned short, (__bf16)b);
    return (unsigned)ua | ((unsigned)ub << 16);
}

// lane i <-> lane i^32 pairwise exchange of two registers (gfx950)
DEV void pswap(unsigned& a, unsigned& b) {
    asm volatile("v_permlane32_swap_b32 %0, %1" : "+v"(a), "+v"(b));
}

// async global->LDS, 16B per lane. LDS dst must be wave-uniform-base + lane*16.
DEV void gload16(const void* g, void* l) {
    __builtin_amdgcn_global_load_lds(
        (const __attribute__((address_space(1))) unsigned int*)(uintptr_t)g,
        (__attribute__((address_space(3))) unsigned int*)(unsigned int)(uintptr_t)l,
        16, 0, 0);
}

// ---------------- fp32 -> bf16 elementwise ----------------
__global__ void k_cvt(const float* __restrict__ in, unsigned short* __restrict__ out, int n4) {
    int i = blockIdx.x * 256 + threadIdx.x;
    int st = gridDim.x * 256;
    for (; i < n4; i += st) {
        f32x4 v = *(const f32x4*)(in + (size_t)i * 4);
        u16x4 o;
        o[0] = f2bf(v[0]); o[1] = f2bf(v[1]); o[2] = f2bf(v[2]); o[3] = f2bf(v[3]);
        *(u16x4*)(out + (size_t)i * 4) = o;
    }
}

// ---------------- fp32 [1024][Nc] -> bf16 [Nc][1024] transpose ----------------
__global__ void k_transpose(const float* __restrict__ in, unsigned short* __restrict__ out, int Nc) {
    __shared__ unsigned short tl[64][68];
    int n0 = blockIdx.x * 64, k0 = blockIdx.y * 64;
#pragma unroll
    for (int i = 0; i < 16; i++) {
        int idx = i * 256 + threadIdx.x;
        int kr = idx >> 6, nc = idx & 63;
        tl[kr][nc] = f2bf(in[(size_t)(k0 + kr) * Nc + n0 + nc]);
    }
    __syncthreads();
#pragma unroll
    for (int i = 0; i < 8; i++) {
        int idx = i * 256 + threadIdx.x;
        int nr = idx >> 5, kp2 = idx & 31;
        unsigned vv = (unsigned)tl[kp2 * 2][nr] | ((unsigned)tl[kp2 * 2 + 1][nr] << 16);
        *(unsigned*)(out + (size_t)(n0 + nr) * 1024 + k0 + kp2 * 2) = vv;
    }
}

// ---------------- GEMM: C[M][N] = A[M][K] * Bt[N][K]^T  (bf16 in, fp32 acc) ----
// MODE 1: scatter q (scaled by SCALE*log2e) / k to [B][H][N][D]; V TRANSPOSED
//         to vT [B][H][D][N].  MODE 3: out fp32 = C + bias (N fixed 1024)
// XCD-aware bijective block swizzle (T1): nwg is 768 / 256, both %8 == 0.
template <int MODE>
__global__ __launch_bounds__(256) void k_gemm(
    const unsigned short* __restrict__ A, const unsigned short* __restrict__ Bt, int K,
    unsigned short* __restrict__ q, unsigned short* __restrict__ kk_,
    unsigned short* __restrict__ vT, const float* __restrict__ bias,
    float* __restrict__ outf) {
    __shared__ unsigned short As[128 * 64];
    __shared__ unsigned short Bs[128 * 64];
    const int tid = threadIdx.x;
    const int w = tid >> 6, l = tid & 63, g = l >> 4, lr = l & 15;
    const int wr = w >> 1, wc = w & 1;
    const int nwg = gridDim.x * gridDim.y, cpx = nwg >> 3;
    const int lin = blockIdx.y * gridDim.x + blockIdx.x;
    const int swz = (lin & 7) * cpx + (lin >> 3);
    const int m0 = (swz / gridDim.x) * 128, n0 = (swz % gridDim.x) * 128;
    f32x4 acc[4][4] = {};

    for (int k0 = 0; k0 < K; k0 += 64) {
        __syncthreads();
#pragma unroll
        for (int i = 0; i < 4; i++) {
            int c = i * 256 + tid;
            gload16(A + (size_t)(m0 + (c >> 3)) * K + k0 + (c & 7) * 8, (char*)As + c * 16);
            gload16(Bt + (size_t)(n0 + (c >> 3)) * K + k0 + (c & 7) * 8, (char*)Bs + c * 16);
        }
        __syncthreads();
#pragma unroll
        for (int kk = 0; kk < 2; kk++) {
            bf16x8 af[4], bfv[4];
#pragma unroll
            for (int mi = 0; mi < 4; mi++)
                af[mi] = *(const bf16x8*)(As + (wr * 64 + mi * 16 + lr) * 64 + kk * 32 + g * 8);
#pragma unroll
            for (int ni = 0; ni < 4; ni++)
                bfv[ni] = *(const bf16x8*)(Bs + (wc * 64 + ni * 16 + lr) * 64 + kk * 32 + g * 8);
#pragma unroll
            for (int mi = 0; mi < 4; mi++)
#pragma unroll
                for (int ni = 0; ni < 4; ni++)
                    acc[mi][ni] = __builtin_amdgcn_mfma_f32_16x16x32_bf16(af[mi], bfv[ni], acc[mi][ni], 0, 0, 0);
        }
    }

#pragma unroll
    for (int mi = 0; mi < 4; mi++) {
#pragma unroll
        for (int ni = 0; ni < 4; ni++) {
            if (MODE == 1) {
                int row0 = m0 + wr * 64 + mi * 16 + g * 4;   // 4-aligned, no b-crossing
                int col = n0 + wc * 64 + ni * 16 + lr;
                int b = row0 >> 11, nn = row0 & 2047;
                int which = col >> 10, cc = col & 1023;
                int h = cc >> 6, d = cc & 63;
                if (which == 2) {
                    u16x4 pv;
#pragma unroll
                    for (int r = 0; r < 4; r++) pv[r] = f2bf(acc[mi][ni][r]);
                    *(u16x4*)&vT[((size_t)(b * 16 + h) * 64 + d) * 2048 + nn] = pv;
                } else {
                    unsigned short* dst = (which == 0) ? q : kk_;
                    const float sc = (which == 0) ? QSCALE_LOG2E : 1.f;
#pragma unroll
                    for (int r = 0; r < 4; r++)
                        dst[((size_t)(b * 16 + h) * 2048 + nn + r) * 64 + d] = f2bf(acc[mi][ni][r] * sc);
                }
            } else {
#pragma unroll
                for (int r = 0; r < 4; r++) {
                    int row = m0 + wr * 64 + mi * 16 + g * 4 + r;
                    int col = n0 + wc * 64 + ni * 16 + lr;
                    outf[(size_t)row * 1024 + col] = acc[mi][ni][r] + bias[col];
                }
            }
        }
    }
}

// ---------------- flash attention: 4 waves = 2 q-groups x 2 KV-halves ---------
// Block 256 thr. Wave w: qg = w>>1 (32 q-rows), kvh = w&1 (KV half, 1024 rows,
// tiles of 32). Waves sharing a KV-half share one DOUBLE-BUFFERED chunk-major
// K/V staging (prefetch t+1 issued at top of iter t -- full iteration in
// flight; round-5 proven pattern). One vmcnt(0)+barrier per iter. Zero bank
// conflicts by construction. XCD-grouped decode keeps each head's K/V in one
// XCD's L2 (round-6 proven: FETCH 70->12MB). End: exact flash merge via LDS.
__global__ __launch_bounds__(256, 4) void k_attn(
    const unsigned short* __restrict__ qb, const unsigned short* __restrict__ kb,
    const unsigned short* __restrict__ vTb, unsigned short* __restrict__ ao) {
    __shared__ __align__(16) char smem[32768];   // [kvh][ K0 K1 V0 V1 ] x 4KB
    const int tid = threadIdx.x;
    const int w = tid >> 6, l = tid & 63, l31 = l & 31, hf = l >> 5;
    const int qg = w >> 1, kvh = w & 1;
    const int hp = qg * 64 + l;                   // 0..127 within half-pair
    // XCD-grouped decode: 1024 blocks = 8 xcd x 4 bh x 32 qb
    const int bid = blockIdx.x;
    const int xcd = bid & 7, slot = bid >> 3;
    const int bh = xcd * 4 + (slot >> 5), qb_ = slot & 31;
    const int b = bh >> 4, h = bh & 15;
    const unsigned short* qp = qb + (size_t)bh * 131072;
    const unsigned short* kp = kb + (size_t)bh * 131072 + (size_t)kvh * 65536;  // +kvh*1024 rows
    const unsigned short* vTp = vTb + (size_t)bh * 131072 + kvh * 1024;         // [d][n], +kvh*1024 col
    char* Kb0 = smem + kvh * 16384;               // K buffers (4KB each)
    char* Vb0 = smem + kvh * 16384 + 8192;        // V buffers (4KB each)

    // Q fragment (B-operand of swapped QK^T): Q[qrow][d = dc*16 + hf*8 + j]
    const int qrow = qb_ * 64 + qg * 32 + l31;
    bf16x8 qf[4];
#pragma unroll
    for (int dc = 0; dc < 4; dc++)
        qf[dc] = *(const bf16x8*)(qp + (size_t)qrow * 64 + dc * 16 + hf * 8);

    f32x16 o_acc[2] = {};   // O^T[d = (r&3)+8(r>>2)+4hf+32dt][q=l31]
    float m_r = -1e30f, l_r = 0.f;

    // staging indices (each half-pair stages its own 8KB tile: 4 gload16/thread)
    const int kc0 = hp >> 5, krow0 = hp & 31;          // K: chunks 0..7, rows 0..31
    const int kc1 = (128 + hp) >> 5, krow1 = hp & 31;  //    (idx 128+hp)
    const int vc0 = hp >> 6, vdr0 = hp & 63;           // V: octets 0..3, d 0..63
    const int vc1 = (128 + hp) >> 6, vdr1 = hp & 63;

    // ---- prologue: stage tile 0 into buf 0 ----
    gload16(kp + (size_t)krow0 * 64 + kc0 * 8, Kb0 + hp * 16);
    gload16(kp + (size_t)krow1 * 64 + kc1 * 8, Kb0 + (128 + hp) * 16);
    gload16(vTp + (size_t)vdr0 * 2048 + vc0 * 8, Vb0 + hp * 16);
    gload16(vTp + (size_t)vdr1 * 2048 + vc1 * 8, Vb0 + (128 + hp) * 16);
    asm volatile("s_waitcnt vmcnt(0)" ::: "memory");
    __syncthreads();

    int cur = 0;
    for (int t = 0; t < 32; ++t) {
        const int nxt = cur ^ 1;
        if (t < 31) {
            const int kv0 = (t + 1) * 32;
            gload16(kp + (size_t)(kv0 + krow0) * 64 + kc0 * 8, Kb0 + nxt * 4096 + hp * 16);
            gload16(kp + (size_t)(kv0 + krow1) * 64 + kc1 * 8, Kb0 + nxt * 4096 + (128 + hp) * 16);
            gload16(vTp + (size_t)vdr0 * 2048 + kv0 + vc0 * 8, Vb0 + nxt * 4096 + hp * 16);
            gload16(vTp + (size_t)vdr1 * 2048 + kv0 + vc1 * 8, Vb0 + nxt * 4096 + (128 + hp) * 16);
        }
        const char* Kl = Kb0 + cur * 4096;
        const char* Vl = Vb0 + cur * 4096;

        // ---- S^T = K x Q (32kv x 32q, k=64 over 4 chunks) ----
        f32x16 s = {};
        __builtin_amdgcn_s_setprio(1);
#pragma unroll
        for (int kt = 0; kt < 4; kt++) {
            bf16x8 kf = *(const bf16x8*)(Kl + ((2 * kt + hf) * 32 + l31) * 16);
            s = __builtin_amdgcn_mfma_f32_32x32x16_bf16(kf, qf[kt], s, 0, 0, 0);
        }
        __builtin_amdgcn_s_setprio(0);

        // ---- lane-local online softmax (base 2), q-row l31 (kv split by hf) --
        float ma = fmaxf(fmaxf(s[0], s[1]), fmaxf(s[2], s[3]));
        float mb = fmaxf(fmaxf(s[4], s[5]), fmaxf(s[6], s[7]));
        float mc = fmaxf(fmaxf(s[8], s[9]), fmaxf(s[10], s[11]));
        float md = fmaxf(fmaxf(s[12], s[13]), fmaxf(s[14], s[15]));
        float mx = fmaxf(fmaxf(ma, mb), fmaxf(mc, md));
        mx = fmaxf(mx, __shfl_xor(mx, 32));
        if (!__all(mx <= m_r + 8.f)) {   // defer-max (T13)
            float mn = fmaxf(m_r, mx);
            float fac = __builtin_amdgcn_exp2f(m_r - mn);
            m_r = mn;
            l_r *= fac;
#pragma unroll
            for (int r = 0; r < 16; r++) { o_acc[0][r] *= fac; o_acc[1][r] *= fac; }
        }
        float s0 = 0.f, s1 = 0.f, s2 = 0.f, s3 = 0.f;
#pragma unroll
        for (int r = 0; r < 16; r += 4) {
            float p0 = __builtin_amdgcn_exp2f(s[r] - m_r);
            float p1 = __builtin_amdgcn_exp2f(s[r + 1] - m_r);
            float p2 = __builtin_amdgcn_exp2f(s[r + 2] - m_r);
            float p3 = __builtin_amdgcn_exp2f(s[r + 3] - m_r);
            s[r] = p0; s[r + 1] = p1; s[r + 2] = p2; s[r + 3] = p3;
            s0 += p0; s1 += p1; s2 += p2; s3 += p3;
        }
        float ssum = (s0 + s1) + (s2 + s3);
        ssum += __shfl_xor(ssum, 32);
        l_r += ssum;

        // ---- pack P -> bf16, permlane32_swap -> PV B-frags ----
        unsigned wd[8];
#pragma unroll
        for (int i = 0; i < 8; i++) wd[i] = pack2bf(s[2 * i], s[2 * i + 1]);
        bf16x8 pf[2];
#pragma unroll
        for (int cl = 0; cl < 2; cl++) {
            unsigned b0 = wd[4 * cl + 0], b2 = wd[4 * cl + 2];
            unsigned b1 = wd[4 * cl + 1], b3 = wd[4 * cl + 3];
            pswap(b0, b2);
            pswap(b1, b3);
            u32x4 bw; bw[0] = b0; bw[1] = b1; bw[2] = b2; bw[3] = b3;
            pf[cl] = __builtin_bit_cast(bf16x8, bw);
        }

        // ---- O^T += V^T x P ----
        __builtin_amdgcn_s_setprio(1);
#pragma unroll
        for (int c2 = 0; c2 < 2; c2++)
#pragma unroll
            for (int dt = 0; dt < 2; dt++) {
                bf16x8 vf = *(const bf16x8*)(Vl + ((2 * c2 + hf) * 64 + dt * 32 + l31) * 16);
                o_acc[dt] = __builtin_amdgcn_mfma_f32_32x32x16_bf16(vf, pf[c2], o_acc[dt], 0, 0, 0);
            }
        __builtin_amdgcn_s_setprio(0);

        asm volatile("s_waitcnt vmcnt(0)" ::: "memory");
        __syncthreads();
        cur = nxt;
    }

    // ---- merge the two KV halves (exact flash merge; pairs (qg, kvh=0/1)) ----
    __syncthreads();
    float* dO = (float*)(smem + qg * 8704);            // [64 lane][34] padded
    float* dM = (float*)(smem + 17408 + qg * 256);
    float* dL = (float*)(smem + 17920 + qg * 256);
    if (kvh == 1) {
#pragma unroll
        for (int i = 0; i < 16; i++) dO[l * 34 + i] = o_acc[0][i];
#pragma unroll
        for (int i = 0; i < 16; i++) dO[l * 34 + 16 + i] = o_acc[1][i];
        dM[l] = m_r;
        dL[l] = l_r;
    }
    __syncthreads();
    if (kvh == 0) {
        float m1 = dM[l], l1 = dL[l];
        float m = fmaxf(m_r, m1);
        float a0 = __builtin_amdgcn_exp2f(m_r - m);
        float a1 = __builtin_amdgcn_exp2f(m1 - m);
        float linv = 1.f / (l_r * a0 + l1 * a1);
        float c0 = a0 * linv, c1 = a1 * linv;
        unsigned short* aop = ao + ((size_t)b * 2048 + qrow) * 1024 + h * 64;
#pragma unroll
        for (int dt = 0; dt < 2; dt++)
#pragma unroll
            for (int rg = 0; rg < 4; rg++) {
                u16x4 pv;
#pragma unroll
                for (int k = 0; k < 4; k++) {
                    int r = rg * 4 + k;
                    pv[k] = f2bf(o_acc[dt][r] * c0 + dO[l * 34 + dt * 16 + r] * c1);
                }
                *(u16x4*)(aop + 8 * rg + 4 * hf + 32 * dt) = pv;
            }
    }
}

extern "C" void kernel_launch(void* const* d_in, const int* in_sizes, int n_in,
                              void* d_out, int out_size, void* d_ws, size_t ws_size,
                              hipStream_t stream) {
    (void)in_sizes; (void)n_in; (void)out_size; (void)ws_size;
    const float* x      = (const float*)d_in[0];
    const float* w_qkv  = (const float*)d_in[1];
    const float* w_proj = (const float*)d_in[2];
    const float* b_proj = (const float*)d_in[3];
    float* out = (float*)d_out;
    char* ws = (char*)d_ws;

    // workspace layout (bytes); ao aliases xb (xb dead after GEMM1)
    unsigned short* xb     = (unsigned short*)(ws);             // [4096][1024] bf16
    unsigned short* ao     = (unsigned short*)(ws);             // [4096][1024] bf16 (alias)
    unsigned short* wqkvT  = (unsigned short*)(ws + 8388608);   // [3072][1024] bf16
    unsigned short* wprojT = (unsigned short*)(ws + 14680064);  // [1024][1024] bf16
    unsigned short* qb     = (unsigned short*)(ws + 16777216);  // [2][16][2048][64] bf16
    unsigned short* kb     = (unsigned short*)(ws + 25165824);  // [2][16][2048][64] bf16
    unsigned short* vTb    = (unsigned short*)(ws + 33554432);  // [2][16][64][2048] bf16

    k_cvt<<<2048, 256, 0, stream>>>(x, xb, 1048576);
    k_transpose<<<dim3(48, 16), 256, 0, stream>>>(w_qkv, wqkvT, 3072);
    k_transpose<<<dim3(16, 16), 256, 0, stream>>>(w_proj, wprojT, 1024);
    k_gemm<1><<<dim3(24, 32), 256, 0, stream>>>(xb, wqkvT, 1024, qb, kb, vTb, nullptr, nullptr);
    k_attn<<<1024, 256, 0, stream>>>(qb, kb, vTb, ao);
    k_gemm<3><<<dim3(8, 32), 256, 0, stream>>>(ao, wprojT, 1024, nullptr, nullptr, nullptr, b_proj, out);
}